// Round 4
// baseline (191.342 us; speedup 1.0000x reference)
//
#include <hip/hip_runtime.h>

#define T_STEPS 512
#define BATCH 64

// fp32 casts of np.exp(-1/20), np.exp(-1/5)
__device__ constexpr float ALPHA_ = 0.95122942450071400910f;
__device__ constexpr float BETA_  = 0.81873075307798185867f;

typedef __attribute__((ext_vector_type(8))) short bf16x8;
typedef __attribute__((ext_vector_type(4))) float f32x4;

__device__ inline unsigned short f2bf_rne(float f) {
  union { float f; unsigned int u; } v{f};
  const unsigned int u = v.u;
  return (unsigned short)((u + 0x7FFFu + ((u >> 16) & 1u)) >> 16);
}
__device__ inline float bf2f(unsigned short h) {
  union { unsigned int u; float f; } v{(unsigned int)h << 16};
  return v.f;
}

// pack trunc-bf16(first) | trunc-bf16(second)<<16  (exact for spike 0/1)
__device__ inline unsigned int pkbf(float first, float second) {
#if __has_builtin(__builtin_amdgcn_perm)
  return __builtin_amdgcn_perm(__float_as_uint(second), __float_as_uint(first),
                               0x07060302u);
#else
  return (__float_as_uint(first) >> 16) | (__float_as_uint(second) & 0xFFFF0000u);
#endif
}

// 8 fp32 (lo = k0..3, hi = k4..7) -> MFMA bf16x8 fragment word order
__device__ inline bf16x8 cvt_frag(const f32x4 lo, const f32x4 hi) {
  union { unsigned int w[4]; bf16x8 v; } u;
  u.w[0] = pkbf(lo.x, lo.y);
  u.w[1] = pkbf(lo.z, lo.w);
  u.w[2] = pkbf(hi.x, hi.y);
  u.w[3] = pkbf(hi.z, hi.w);
  return u.v;
}

// ---------------------------------------------------------------------------
// Barrier-free wave-level MFMA GEMM. Each wave owns a 64x64 C tile.
// No LDS, no __syncthreads: A fragments are loaded straight from global
// (fp32 rows -> in-register trunc to bf16, exact for spikes; or bf16 rows),
// B hi/lo are in fragment-linear global layout (prep_split<64>), so each
// lane's fragment is one contiguous dwordx4. Depth-1 ping-pong register
// prefetch with statically-named reg sets.
// wid = wr*NWC + wc; consecutive waves (same block) share A rows -> L1 reuse.
// Epilogue: LNFOLD ? inv[r]*acc - mi[r]*u[c] + cvec[c] : acc + cvec[c].
// ---------------------------------------------------------------------------
template <int NWC, bool A_F32, bool LNFOLD>
__global__ __launch_bounds__(256) void gemm_wave(
    const void* __restrict__ Av, const char* __restrict__ Bhi,
    const char* __restrict__ Blo, const float* __restrict__ uvec,
    const float* __restrict__ cvec, const float* __restrict__ invv,
    const float* __restrict__ miv, float* __restrict__ C, int N, int K) {
  const int tid = threadIdx.x;
  const int lane = tid & 63;
  const int wid = blockIdx.x * 4 + (tid >> 6);
  const int wr = wid / NWC, wc = wid % NWC;   // NWC is 1/2/4 -> shifts
  const int l15 = lane & 15, l4 = lane >> 4;
  const int row0 = wr * 64, col0 = wc * 64;
  const int KB = K / 32;

  const char* Ab = (const char*)Av;
  size_t a_off[4];
#pragma unroll
  for (int m = 0; m < 4; ++m)
    a_off[m] = ((size_t)(row0 + m * 16 + l15) * K + l4 * 8) * (A_F32 ? 4 : 2);

  // B frag-linear: unit (n<<6)+lane at ((wc*KB + kb)*256 + unit)*16 bytes
  const char* bh_p = Bhi + (size_t)wc * KB * 4096 + (size_t)lane * 16;
  const char* bl_p = Blo + (size_t)wc * KB * 4096 + (size_t)lane * 16;

  f32x4 acc[4][4] = {};
  f32x4 lo0[4], hi0[4], lo1[4], hi1[4];
  bf16x8 ab0[4], ab1[4], bh0[4], bl0[4], bh1[4], bl1[4];

  auto loadA = [&](int kb, f32x4 (&lo)[4], f32x4 (&hi)[4], bf16x8 (&ab)[4]) {
#pragma unroll
    for (int m = 0; m < 4; ++m) {
      if constexpr (A_F32) {
        const float* p = (const float*)(Ab + a_off[m] + (size_t)kb * 128);
        lo[m] = *(const f32x4*)p;
        hi[m] = *(const f32x4*)(p + 4);
      } else {
        ab[m] = *(const bf16x8*)(Ab + a_off[m] + (size_t)kb * 64);
      }
    }
  };
  auto loadB = [&](int kb, bf16x8 (&bh)[4], bf16x8 (&bl)[4]) {
    const char* ph = bh_p + (size_t)kb * 4096;
    const char* pl = bl_p + (size_t)kb * 4096;
#pragma unroll
    for (int n = 0; n < 4; ++n) {
      bh[n] = *(const bf16x8*)(ph + n * 1024);
      bl[n] = *(const bf16x8*)(pl + n * 1024);
    }
  };
  auto compute = [&](f32x4 (&lo)[4], f32x4 (&hi)[4], bf16x8 (&ab)[4],
                     bf16x8 (&bh)[4], bf16x8 (&bl)[4]) {
    bf16x8 af[4];
#pragma unroll
    for (int m = 0; m < 4; ++m) {
      if constexpr (A_F32) af[m] = cvt_frag(lo[m], hi[m]);
      else af[m] = ab[m];
    }
#pragma unroll
    for (int m = 0; m < 4; ++m)
#pragma unroll
      for (int n = 0; n < 4; ++n) {
        acc[m][n] = __builtin_amdgcn_mfma_f32_16x16x32_bf16(af[m], bh[n], acc[m][n], 0, 0, 0);
        acc[m][n] = __builtin_amdgcn_mfma_f32_16x16x32_bf16(af[m], bl[n], acc[m][n], 0, 0, 0);
      }
  };

  loadA(0, lo0, hi0, ab0);
  loadB(0, bh0, bl0);
  for (int kb = 0; kb < KB; kb += 2) {    // KB even for all layers (32/8/4)
    loadA(kb + 1, lo1, hi1, ab1);
    loadB(kb + 1, bh1, bl1);
    compute(lo0, hi0, ab0, bh0, bl0);
    if (kb + 2 < KB) {
      loadA(kb + 2, lo0, hi0, ab0);
      loadB(kb + 2, bh0, bl0);
    }
    compute(lo1, hi1, ab1, bh1, bl1);
  }

#pragma unroll
  for (int m = 0; m < 4; ++m) {
    const int rbase = row0 + m * 16 + l4 * 4;
    f32x4 iv{}, mv{};
    if constexpr (LNFOLD) {
      iv = *(const f32x4*)(invv + rbase);
      mv = *(const f32x4*)(miv + rbase);
    }
#pragma unroll
    for (int n = 0; n < 4; ++n) {
      const int c = col0 + n * 16 + l15;
      const float cc = cvec[c];
      float uu = 0.f;
      if constexpr (LNFOLD) uu = uvec[c];
#pragma unroll
      for (int r = 0; r < 4; ++r) {
        float v;
        if constexpr (LNFOLD) v = iv[r] * acc[m][n][r] - mv[r] * uu + cc;
        else v = acc[m][n][r] + cc;
        C[(size_t)(rbase + r) * N + c] = v;
      }
    }
  }
}

// ---------------------------------------------------------------------------
// Prep: W[K,N] f32 (optionally scaled by s[k]) -> split hi/lo bf16 in the
// fragment-linear (BN=64) global layout consumed by gemm_wave.
// ---------------------------------------------------------------------------
template <int BN>
__global__ void prep_split(const float* __restrict__ W, const float* __restrict__ s,
                           char* __restrict__ hi, char* __restrict__ lo,
                           int K, int N) {
  const int g = blockIdx.x * 256 + threadIdx.x;
  const int total = (K * N) / 8;
  if (g >= total) return;
  constexpr int UB = BN * 4;
  const int KB = K / 32;
  const int unit = g % UB;
  const int kb = (g / UB) % KB;
  const int cb = g / (UB * KB);
  const int n = cb * BN + ((unit >> 6) << 4) + (unit & 15);
  const int kbase = kb * 32 + ((unit >> 4) & 3) * 8;
  short h8[8], l8[8];
#pragma unroll
  for (int jj = 0; jj < 8; ++jj) {
    const int k = kbase + jj;
    float w = W[(size_t)k * N + n];
    if (s) w *= s[k];
    const unsigned short hb = f2bf_rne(w);
    const unsigned short lb = f2bf_rne(w - bf2f(hb));
    h8[jj] = (short)hb; l8[jj] = (short)lb;
  }
  *(bf16x8*)(hi + (size_t)g * 16) = *(const bf16x8*)h8;
  *(bf16x8*)(lo + (size_t)g * 16) = *(const bf16x8*)l8;
}

// u[n] = sum_k s[k]*W[k,n];  c[n] = sum_k b[k]*W[k,n] + bias2[n]. Block per n.
__global__ __launch_bounds__(256) void prep_consts(
    const float* __restrict__ W, const float* __restrict__ s,
    const float* __restrict__ b, const float* __restrict__ bias2,
    float* __restrict__ u, float* __restrict__ c, int K, int N) {
  const int n = blockIdx.x;
  const int t = threadIdx.x;
  float us = 0.f, cs = 0.f;
  for (int k = t; k < K; k += 256) {
    const float w = W[(size_t)k * N + n];
    us += s[k] * w;
    cs += b[k] * w;
  }
  __shared__ float su[256], sc[256];
  su[t] = us; sc[t] = cs;
  __syncthreads();
  for (int o = 128; o > 0; o >>= 1) {
    if (t < o) { su[t] += su[t + o]; sc[t] += sc[t + o]; }
    __syncthreads();
  }
  if (t == 0) { u[n] = su[0]; c[n] = sc[0] + bias2[n]; }
}

// ---------------------------------------------------------------------------
// Row stats of a spike matrix (values in {0,1}): mean m = rowsum/K,
// var = m*(1-m)  (since x^2 = x), inv = 1/sqrt(var+eps). One wave per row.
// ---------------------------------------------------------------------------
template <int K>
__global__ __launch_bounds__(256) void rowstats(
    const unsigned short* __restrict__ sp, float* __restrict__ invv,
    float* __restrict__ miv) {
  const int wave = threadIdx.x >> 6, lane = threadIdx.x & 63;
  const int row = blockIdx.x * 4 + wave;
  const unsigned short* p = sp + (size_t)row * K;
  float ssum = 0.f;
  if constexpr (K == 256) {
    const ushort4 v = *(const ushort4*)(p + lane * 4);
    ssum = bf2f(v.x) + bf2f(v.y) + bf2f(v.z) + bf2f(v.w);
  } else {  // K == 128
    const ushort2 v = *(const ushort2*)(p + lane * 2);
    ssum = bf2f(v.x) + bf2f(v.y);
  }
#pragma unroll
  for (int o = 32; o > 0; o >>= 1) ssum += __shfl_xor(ssum, o);
  if (lane == 0) {
    const float m = ssum / (float)K;
    const float inv = 1.0f / sqrtf(m * (1.f - m) + 1e-6f);
    invv[row] = inv;
    miv[row] = m * inv;
  }
}

// ---------------------------------------------------------------------------
// LIF scan over T, one thread per (b,h); reads fp32 currents, writes bf16
// spikes (exact) and/or per-(b,h) spike counts. 16x unrolled loads.
// ---------------------------------------------------------------------------
template <int H, bool SPIKE_OUT, bool ACCUM>
__global__ void lif_scan(const float* __restrict__ xt,
                         unsigned short* __restrict__ sp,
                         float* __restrict__ tsum) {
  const int n = blockIdx.x * 64 + threadIdx.x;
  const int b = n / H, h = n % H;
  const float* p = xt + (size_t)b * T_STEPS * H + h;
  unsigned short* q = nullptr;
  if constexpr (SPIKE_OUT) q = sp + (size_t)b * T_STEPS * H + h;

  float v = 0.f, cur = 0.f, ts = 0.f;
  for (int t = 0; t < T_STEPS; t += 16) {
    float x[16];
#pragma unroll
    for (int u = 0; u < 16; ++u) x[u] = p[(size_t)u * H];
#pragma unroll
    for (int u = 0; u < 16; ++u) {
      cur = BETA_ * cur + x[u];
      v = ALPHA_ * v + cur;
      const bool sb = (v >= 1.f);
      if constexpr (SPIKE_OUT) q[(size_t)u * H] = sb ? 0x3F80 : 0;
      if constexpr (ACCUM) ts += sb ? 1.f : 0.f;
      v = sb ? 0.f : v;
    }
    p += (size_t)16 * H;
    if constexpr (SPIKE_OUT) q += (size_t)16 * H;
  }
  if constexpr (ACCUM) tsum[n] = ts;
}

__global__ void finalize(const float* __restrict__ tsum,
                         const float* __restrict__ Wc,
                         const float* __restrict__ bc,
                         float* __restrict__ out) {
  const int b = threadIdx.x;  // 64 threads, one wave
  float s = 0.f;
#pragma unroll 8
  for (int h = 0; h < 64; ++h) s += tsum[b * 64 + h];
  const float pooled = s * (1.0f / (512.f * 64.f));
  out[2 + b] = pooled;

  float tot = pooled;
  float l0 = pooled * Wc[b * 2 + 0];
  float l1 = pooled * Wc[b * 2 + 1];
#pragma unroll
  for (int off = 32; off > 0; off >>= 1) {
    tot += __shfl_xor(tot, off);
    l0 += __shfl_xor(l0, off);
    l1 += __shfl_xor(l1, off);
  }
  if (b == 0) {
    out[0] = l0 + bc[0];
    out[1] = l1 + bc[1];
    out[66] = tot * (1.0f / 64.f);
  }
}

extern "C" void kernel_launch(void* const* d_in, const int* in_sizes, int n_in,
                              void* d_out, int out_size, void* d_ws, size_t ws_size,
                              hipStream_t stream) {
  const float* X    = (const float*)d_in[0];   // [64,512,64,16] -> [32768,1024]
  const float* W0   = (const float*)d_in[1];   // [1024,256]
  const float* b0   = (const float*)d_in[2];
  const float* W1   = (const float*)d_in[3];   // [256,128]
  const float* b1   = (const float*)d_in[4];
  const float* W2   = (const float*)d_in[5];   // [128,64]
  const float* b2   = (const float*)d_in[6];
  const float* ln1s = (const float*)d_in[7];
  const float* ln1b = (const float*)d_in[8];
  const float* ln2s = (const float*)d_in[9];
  const float* ln2b = (const float*)d_in[10];
  const float* Wc   = (const float*)d_in[11];  // [64,2]
  const float* bc   = (const float*)d_in[12];
  float* out = (float*)d_out;

  char* w = (char*)d_ws;
  float* buf0 = (float*)w;                       // [32768,256] f32 = 33554432 B
  float* buf1 = (float*)w;                       // alias: buf0 dead after scan0
  float* buf2 = (float*)(w + 16777216);          // [32768,64] f32, after buf1
  size_t off = 33554432;
  unsigned short* sp0 = (unsigned short*)(w + off); off += 16777216;  // [32768,256] bf16
  unsigned short* sp1 = (unsigned short*)(w + off); off += 8388608;   // [32768,128] bf16
  char* hi0 = w + off; off += 524288;
  char* lo0 = w + off; off += 524288;
  char* hi1 = w + off; off += 65536;
  char* lo1 = w + off; off += 65536;
  char* hi2 = w + off; off += 16384;
  char* lo2 = w + off; off += 16384;
  float* u1 = (float*)(w + off); off += 512;
  float* c1 = (float*)(w + off); off += 512;
  float* u2 = (float*)(w + off); off += 256;
  float* c2 = (float*)(w + off); off += 256;
  float* inv1 = (float*)(w + off); off += 131072;
  float* mi1  = (float*)(w + off); off += 131072;
  float* inv2 = (float*)(w + off); off += 131072;
  float* mi2  = (float*)(w + off); off += 131072;
  float* tsum = (float*)(w + off); off += 16384;

  const int M = 32768;

  // --- weight prep (frag-linear BN=64 split hi/lo + LN-fold constants) ---
  prep_split<64><<<128, 256, 0, stream>>>(W0, nullptr, hi0, lo0, 1024, 256);
  prep_split<64><<<16, 256, 0, stream>>>(W1, ln1s, hi1, lo1, 256, 128);
  prep_split<64><<<4, 256, 0, stream>>>(W2, ln2s, hi2, lo2, 128, 64);
  prep_consts<<<128, 256, 0, stream>>>(W1, ln1s, ln1b, b1, u1, c1, 256, 128);
  prep_consts<<<64, 256, 0, stream>>>(W2, ln2s, ln2b, b2, u2, c2, 128, 64);

  // --- layer 0: xt = X @ W0 + b0 ; scan -> bf16 spikes ---
  // waves = (M/64) * (256/64) = 2048 -> 512 blocks
  gemm_wave<4, true, false><<<512, 256, 0, stream>>>(
      X, hi0, lo0, nullptr, b0, nullptr, nullptr, buf0, 256, 1024);
  lif_scan<256, true, false><<<(BATCH * 256) / 64, 64, 0, stream>>>(buf0, sp0, nullptr);

  // --- layer 1: LN folded into GEMM (spike rows: var = m(1-m)) ---
  rowstats<256><<<M / 4, 256, 0, stream>>>(sp0, inv1, mi1);
  // waves = 512 * 2 = 1024 -> 256 blocks
  gemm_wave<2, false, true><<<256, 256, 0, stream>>>(
      sp0, hi1, lo1, u1, c1, inv1, mi1, buf1, 128, 256);
  lif_scan<128, true, false><<<(BATCH * 128) / 64, 64, 0, stream>>>(buf1, sp1, nullptr);

  // --- layer 2 ---
  rowstats<128><<<M / 4, 256, 0, stream>>>(sp1, inv2, mi2);
  // waves = 512 * 1 = 512 -> 128 blocks
  gemm_wave<1, false, true><<<128, 256, 0, stream>>>(
      sp1, hi2, lo2, u2, c2, inv2, mi2, buf2, 64, 128);
  lif_scan<64, false, true><<<(BATCH * 64) / 64, 64, 0, stream>>>(buf2, nullptr, tsum);

  finalize<<<1, 64, 0, stream>>>(tsum, Wc, bc, out);
}

// Round 5
// 141.190 us; speedup vs baseline: 1.3552x; 1.3552x over previous
//
#include <hip/hip_runtime.h>

#define T_STEPS 512
#define BATCH 64

// fp32 casts of np.exp(-1/20), np.exp(-1/5)
__device__ constexpr float ALPHA_ = 0.95122942450071400910f;
__device__ constexpr float BETA_  = 0.81873075307798185867f;

typedef __attribute__((ext_vector_type(8))) short bf16x8;
typedef __attribute__((ext_vector_type(4))) float f32x4;

__device__ inline unsigned short f2bf_rne(float f) {
  union { float f; unsigned int u; } v{f};
  const unsigned int u = v.u;
  return (unsigned short)((u + 0x7FFFu + ((u >> 16) & 1u)) >> 16);
}
__device__ inline float bf2f(unsigned short h) {
  union { unsigned int u; float f; } v{(unsigned int)h << 16};
  return v.f;
}

__device__ inline void gload16(const void* g, void* l) {
  __builtin_amdgcn_global_load_lds(
      (const __attribute__((address_space(1))) unsigned int*)g,
      (__attribute__((address_space(3))) unsigned int*)l, 16, 0, 0);
}

// pack trunc-bf16(first) | trunc-bf16(second)<<16  (exact for spike 0/1)
__device__ inline unsigned int pkbf(float first, float second) {
#if __has_builtin(__builtin_amdgcn_perm)
  return __builtin_amdgcn_perm(__float_as_uint(second), __float_as_uint(first),
                               0x07060302u);
#else
  return (__float_as_uint(first) >> 16) | (__float_as_uint(second) & 0xFFFF0000u);
#endif
}

// 8 fp32 (lo = k0..3, hi = k4..7) -> MFMA bf16x8 fragment word order
__device__ inline bf16x8 cvt_frag(const f32x4 lo, const f32x4 hi) {
  union { unsigned int w[4]; bf16x8 v; } u;
  u.w[0] = pkbf(lo.x, lo.y);
  u.w[1] = pkbf(lo.z, lo.w);
  u.w[2] = pkbf(hi.x, hi.y);
  u.w[3] = pkbf(hi.z, hi.w);
  return u.v;
}

// ---------------------------------------------------------------------------
// 2-phase double-buffered MFMA GEMM (T3 minimum recipe):
//   per K-step: {issue next-tile stage} -> ds_read cur -> MFMA -> write/drain
//   -> ONE __syncthreads. Loads overlap compute; 1 barrier/step.
// Waves: WM x WC grid of wave tiles, wave tile = TM x 64. BM=WM*TM, BN=WC*64.
// LDS frag-linear (all ds ops base+lane*16, conflict-free).
// A: fp32 (reg-stage + trunc->bf16, exact for spikes) or bf16 (gload_lds).
// B: split hi/lo bf16, frag-linear in global (prep_split), gload_lds direct.
// LNFOLD: rowsum computed IN-GEMM via B=ones MFMA (exact for integer counts);
//   epilogue applies inv[r]*acc - mi[r]*u[c] + c[c] with inv,mi from rowsum.
// ---------------------------------------------------------------------------
template <int WM, int WC, int TM, bool A_F32, bool LNFOLD>
__global__ __launch_bounds__(256) void gemm_pipe(
    const void* __restrict__ Av, const char* __restrict__ Bhi,
    const char* __restrict__ Blo, const float* __restrict__ uvec,
    const float* __restrict__ cvec, float* __restrict__ C, int N, int K) {
  constexpr int BM = WM * TM;
  constexpr int BN = WC * 64;
  constexpr int FM = TM / 16;         // m-frags per wave
  constexpr int ABY = BM * 64;        // A bytes/step (BM*32 bf16)
  constexpr int BBY = BN * 64;        // B bytes/step per half (hi)
  constexpr int BUFBY = ABY + 2 * BBY;
  __shared__ char smem[2 * BUFBY];

  const int tid = threadIdx.x;
  const int lane = tid & 63;
  const int wave = tid >> 6;
  const int wm = wave / WC, wc = wave % WC;
  const int l15 = lane & 15, l4 = lane >> 4;
  const int row0 = blockIdx.y * BM;
  const int col0 = blockIdx.x * BN;
  const int KB = K / 32;

  const char* Ab = (const char*)Av;

  // A fp32 staging addresses (BM=128 layout: rows tid>>2 and +64)
  const float* ap0 = nullptr;
  const float* ap1 = nullptr;
  int au0 = 0, au1 = 0;
  if constexpr (A_F32) {
    const int r0 = tid >> 2, j0 = tid & 3;
    ap0 = (const float*)Ab + (size_t)(row0 + r0) * K + j0 * 8;
    ap1 = ap0 + (size_t)64 * K;
    au0 = ((r0 >> 4) << 6) + (j0 << 4) + (r0 & 15);
    au1 = au0 + 256;
  }

  f32x4 acc[FM][4] = {};
  f32x4 acc1[FM] = {};
  const bf16x8 ONES = {0x3F80, 0x3F80, 0x3F80, 0x3F80,
                       0x3F80, 0x3F80, 0x3F80, 0x3F80};

  f32x4 a0, a1, a2, a3;  // fp32 A staging regs (named, static)

  // ---- prologue: stage kb=0 into buffer 0 ----
  {
    char* Abuf = smem;
    char* Bh = smem + ABY;
    char* Bl = Bh + BBY;
    if constexpr (A_F32) {
      a0 = *(const f32x4*)(ap0);
      a1 = *(const f32x4*)(ap0 + 4);
      a2 = *(const f32x4*)(ap1);
      a3 = *(const f32x4*)(ap1 + 4);
    } else {
#pragma unroll
      for (int i = 0; i < BM / 64; ++i) {
        const int unit = i * 256 + tid;
        const int r = ((unit >> 6) << 4) | (unit & 15);
        const int j = (unit >> 4) & 3;
        gload16(Ab + ((size_t)(row0 + r) * K + j * 8) * 2, Abuf + unit * 16);
      }
    }
#pragma unroll
    for (int g = 0; g < WC; ++g) {
      const size_t so = (((size_t)(blockIdx.x * WC + g) * KB) * 256 + tid) * 16;
      gload16(Bhi + so, Bh + (g * 256 + tid) * 16);
      gload16(Blo + so, Bl + (g * 256 + tid) * 16);
    }
    if constexpr (A_F32) {
      *(bf16x8*)(Abuf + au0 * 16) = cvt_frag(a0, a1);
      *(bf16x8*)(Abuf + au1 * 16) = cvt_frag(a2, a3);
    }
    __syncthreads();
  }

  int cur = 0;
  for (int kb = 0; kb < KB; ++kb) {
    char* bufc = smem + cur * BUFBY;
    char* bufn = smem + (cur ^ 1) * BUFBY;
    const bool pf = (kb + 1 < KB);

    // --- issue next-tile stage (overlaps this tile's ds_read+MFMA) ---
    if (pf) {
      if constexpr (A_F32) {
        const float* p0 = ap0 + (size_t)(kb + 1) * 32;
        const float* p1 = ap1 + (size_t)(kb + 1) * 32;
        a0 = *(const f32x4*)p0;
        a1 = *(const f32x4*)(p0 + 4);
        a2 = *(const f32x4*)p1;
        a3 = *(const f32x4*)(p1 + 4);
      } else {
#pragma unroll
        for (int i = 0; i < BM / 64; ++i) {
          const int unit = i * 256 + tid;
          const int r = ((unit >> 6) << 4) | (unit & 15);
          const int j = (unit >> 4) & 3;
          gload16(Ab + ((size_t)(row0 + r) * K + (kb + 1) * 32 + j * 8) * 2,
                  bufn + unit * 16);
        }
      }
#pragma unroll
      for (int g = 0; g < WC; ++g) {
        const size_t so =
            (((size_t)(blockIdx.x * WC + g) * KB + (kb + 1)) * 256 + tid) * 16;
        gload16(Bhi + so, bufn + ABY + (g * 256 + tid) * 16);
        gload16(Blo + so, bufn + ABY + BBY + (g * 256 + tid) * 16);
      }
    }

    // --- ds_read current fragments (frag-linear: base + lane*16) ---
    bf16x8 af[FM], bh[4], bl[4];
#pragma unroll
    for (int m = 0; m < FM; ++m)
      af[m] = *(const bf16x8*)(bufc + ((wm * FM + m) * 64 + lane) * 16);
#pragma unroll
    for (int n = 0; n < 4; ++n) {
      bh[n] = *(const bf16x8*)(bufc + ABY + (wc * 256 + n * 64 + lane) * 16);
      bl[n] = *(const bf16x8*)(bufc + ABY + BBY + (wc * 256 + n * 64 + lane) * 16);
    }

#pragma unroll
    for (int m = 0; m < FM; ++m) {
#pragma unroll
      for (int n = 0; n < 4; ++n) {
        acc[m][n] = __builtin_amdgcn_mfma_f32_16x16x32_bf16(af[m], bh[n], acc[m][n], 0, 0, 0);
        acc[m][n] = __builtin_amdgcn_mfma_f32_16x16x32_bf16(af[m], bl[n], acc[m][n], 0, 0, 0);
      }
      if constexpr (LNFOLD)
        acc1[m] = __builtin_amdgcn_mfma_f32_16x16x32_bf16(af[m], ONES, acc1[m], 0, 0, 0);
    }

    if (pf && A_F32) {
      *(bf16x8*)(bufn + au0 * 16) = cvt_frag(a0, a1);
      *(bf16x8*)(bufn + au1 * 16) = cvt_frag(a2, a3);
    }
    __syncthreads();  // drains gload_lds (vmcnt) + ds_write; next buf ready
    cur ^= 1;
  }

  // ---- epilogue ----
  const int row0w = row0 + wm * TM;
  const int col0w = col0 + wc * 64;
#pragma unroll
  for (int m = 0; m < FM; ++m) {
    const int rbase = row0w + m * 16 + l4 * 4;
    float iv[4], mv[4];
    if constexpr (LNFOLD) {
#pragma unroll
      for (int r = 0; r < 4; ++r) {
        const float mean = acc1[m][r] / (float)K;
        const float inv = 1.0f / sqrtf(mean * (1.f - mean) + 1e-6f);
        iv[r] = inv;
        mv[r] = mean * inv;
      }
    }
#pragma unroll
    for (int n = 0; n < 4; ++n) {
      const int c = col0w + n * 16 + l15;
      const float cc = cvec[c];
      float uu = 0.f;
      if constexpr (LNFOLD) uu = uvec[c];
#pragma unroll
      for (int r = 0; r < 4; ++r) {
        float v;
        if constexpr (LNFOLD) v = iv[r] * acc[m][n][r] - mv[r] * uu + cc;
        else v = acc[m][n][r] + cc;
        C[(size_t)(rbase + r) * N + c] = v;
      }
    }
  }
}

// ---------------------------------------------------------------------------
// Prep: W[K,N] f32 (optionally scaled by s[k]) -> split hi/lo bf16 in the
// fragment-linear (64-col-block) global layout consumed by gemm_pipe.
// ---------------------------------------------------------------------------
__global__ void prep_split(const float* __restrict__ W, const float* __restrict__ s,
                           char* __restrict__ hi, char* __restrict__ lo,
                           int K, int N) {
  const int g = blockIdx.x * 256 + threadIdx.x;
  const int total = (K * N) / 8;
  if (g >= total) return;
  constexpr int UB = 256;  // units per (col-block, K-step)
  const int KB = K / 32;
  const int unit = g % UB;
  const int kb = (g / UB) % KB;
  const int cb = g / (UB * KB);
  const int n = cb * 64 + ((unit >> 6) << 4) + (unit & 15);
  const int kbase = kb * 32 + ((unit >> 4) & 3) * 8;
  short h8[8], l8[8];
#pragma unroll
  for (int jj = 0; jj < 8; ++jj) {
    const int k = kbase + jj;
    float w = W[(size_t)k * N + n];
    if (s) w *= s[k];
    const unsigned short hb = f2bf_rne(w);
    const unsigned short lb = f2bf_rne(w - bf2f(hb));
    h8[jj] = (short)hb;
    l8[jj] = (short)lb;
  }
  *(bf16x8*)(hi + (size_t)g * 16) = *(const bf16x8*)h8;
  *(bf16x8*)(lo + (size_t)g * 16) = *(const bf16x8*)l8;
}

// u[n] = sum_k s[k]*W[k,n];  c[n] = sum_k b[k]*W[k,n] + bias2[n]. Block per n.
__global__ __launch_bounds__(256) void prep_consts(
    const float* __restrict__ W, const float* __restrict__ s,
    const float* __restrict__ b, const float* __restrict__ bias2,
    float* __restrict__ u, float* __restrict__ c, int K, int N) {
  const int n = blockIdx.x;
  const int t = threadIdx.x;
  float us = 0.f, cs = 0.f;
  for (int k = t; k < K; k += 256) {
    const float w = W[(size_t)k * N + n];
    us += s[k] * w;
    cs += b[k] * w;
  }
  __shared__ float su[256], sc[256];
  su[t] = us;
  sc[t] = cs;
  __syncthreads();
  for (int o = 128; o > 0; o >>= 1) {
    if (t < o) { su[t] += su[t + o]; sc[t] += sc[t + o]; }
    __syncthreads();
  }
  if (t == 0) { u[n] = su[0]; c[n] = sc[0] + bias2[n]; }
}

// ---------------------------------------------------------------------------
// LIF scan over T, one thread per (b,h); reads fp32 currents, writes bf16
// spikes (exact) and/or per-(b,h) spike counts. 16x unrolled loads.
// ---------------------------------------------------------------------------
template <int H, bool SPIKE_OUT, bool ACCUM>
__global__ void lif_scan(const float* __restrict__ xt,
                         unsigned short* __restrict__ sp,
                         float* __restrict__ tsum) {
  const int n = blockIdx.x * 64 + threadIdx.x;
  const int b = n / H, h = n % H;
  const float* p = xt + (size_t)b * T_STEPS * H + h;
  unsigned short* q = nullptr;
  if constexpr (SPIKE_OUT) q = sp + (size_t)b * T_STEPS * H + h;

  float v = 0.f, cur = 0.f, ts = 0.f;
  for (int t = 0; t < T_STEPS; t += 16) {
    float x[16];
#pragma unroll
    for (int u = 0; u < 16; ++u) x[u] = p[(size_t)u * H];
#pragma unroll
    for (int u = 0; u < 16; ++u) {
      cur = BETA_ * cur + x[u];
      v = ALPHA_ * v + cur;
      const bool sb = (v >= 1.f);
      if constexpr (SPIKE_OUT) q[(size_t)u * H] = sb ? 0x3F80 : 0;
      if constexpr (ACCUM) ts += sb ? 1.f : 0.f;
      v = sb ? 0.f : v;
    }
    p += (size_t)16 * H;
    if constexpr (SPIKE_OUT) q += (size_t)16 * H;
  }
  if constexpr (ACCUM) tsum[n] = ts;
}

__global__ void finalize(const float* __restrict__ tsum,
                         const float* __restrict__ Wc,
                         const float* __restrict__ bc,
                         float* __restrict__ out) {
  const int b = threadIdx.x;  // 64 threads, one wave
  float s = 0.f;
#pragma unroll 8
  for (int h = 0; h < 64; ++h) s += tsum[b * 64 + h];
  const float pooled = s * (1.0f / (512.f * 64.f));
  out[2 + b] = pooled;

  float tot = pooled;
  float l0 = pooled * Wc[b * 2 + 0];
  float l1 = pooled * Wc[b * 2 + 1];
#pragma unroll
  for (int off = 32; off > 0; off >>= 1) {
    tot += __shfl_xor(tot, off);
    l0 += __shfl_xor(l0, off);
    l1 += __shfl_xor(l1, off);
  }
  if (b == 0) {
    out[0] = l0 + bc[0];
    out[1] = l1 + bc[1];
    out[66] = tot * (1.0f / 64.f);
  }
}

extern "C" void kernel_launch(void* const* d_in, const int* in_sizes, int n_in,
                              void* d_out, int out_size, void* d_ws, size_t ws_size,
                              hipStream_t stream) {
  const float* X    = (const float*)d_in[0];   // [64,512,64,16] -> [32768,1024]
  const float* W0   = (const float*)d_in[1];   // [1024,256]
  const float* b0   = (const float*)d_in[2];
  const float* W1   = (const float*)d_in[3];   // [256,128]
  const float* b1   = (const float*)d_in[4];
  const float* W2   = (const float*)d_in[5];   // [128,64]
  const float* b2   = (const float*)d_in[6];
  const float* ln1s = (const float*)d_in[7];
  const float* ln1b = (const float*)d_in[8];
  const float* ln2s = (const float*)d_in[9];
  const float* ln2b = (const float*)d_in[10];
  const float* Wc   = (const float*)d_in[11];  // [64,2]
  const float* bc   = (const float*)d_in[12];
  float* out = (float*)d_out;

  char* w = (char*)d_ws;
  float* buf0 = (float*)w;                       // [32768,256] f32 = 33554432 B
  float* buf1 = (float*)w;                       // alias: buf0 dead after scan0
  float* buf2 = (float*)(w + 16777216);          // [32768,64] f32, after buf1
  size_t off = 33554432;
  unsigned short* sp0 = (unsigned short*)(w + off); off += 16777216;  // [32768,256] bf16
  unsigned short* sp1 = (unsigned short*)(w + off); off += 8388608;   // [32768,128] bf16
  char* hi0 = w + off; off += 524288;
  char* lo0 = w + off; off += 524288;
  char* hi1 = w + off; off += 65536;
  char* lo1 = w + off; off += 65536;
  char* hi2 = w + off; off += 16384;
  char* lo2 = w + off; off += 16384;
  float* u1 = (float*)(w + off); off += 512;
  float* c1 = (float*)(w + off); off += 512;
  float* u2 = (float*)(w + off); off += 256;
  float* c2 = (float*)(w + off); off += 256;
  float* tsum = (float*)(w + off); off += 16384;

  const int M = 32768;

  // --- weight prep (frag-linear 64-col-block split hi/lo + LN-fold consts) ---
  prep_split<<<128, 256, 0, stream>>>(W0, nullptr, hi0, lo0, 1024, 256);
  prep_split<<<16, 256, 0, stream>>>(W1, ln1s, hi1, lo1, 256, 128);
  prep_split<<<4, 256, 0, stream>>>(W2, ln2s, hi2, lo2, 128, 64);
  prep_consts<<<128, 256, 0, stream>>>(W1, ln1s, ln1b, b1, u1, c1, 256, 128);
  prep_consts<<<64, 256, 0, stream>>>(W2, ln2s, ln2b, b2, u2, c2, 128, 64);

  // --- layer 0: xt = X @ W0 + b0 (2x2 waves, 64x64 wave tile, BM=BN=128) ---
  gemm_pipe<2, 2, 64, true, false><<<dim3(2, M / 128), 256, 0, stream>>>(
      X, hi0, lo0, nullptr, b0, buf0, 256, 1024);
  lif_scan<256, true, false><<<(BATCH * 256) / 64, 64, 0, stream>>>(buf0, sp0, nullptr);

  // --- layer 1: LN folded (rowsum via ones-MFMA), BM=128, BN=64 ---
  gemm_pipe<4, 1, 32, false, true><<<dim3(2, M / 128), 256, 0, stream>>>(
      sp0, hi1, lo1, u1, c1, buf1, 128, 256);
  lif_scan<128, true, false><<<(BATCH * 128) / 64, 64, 0, stream>>>(buf1, sp1, nullptr);

  // --- layer 2 ---
  gemm_pipe<4, 1, 32, false, true><<<dim3(1, M / 128), 256, 0, stream>>>(
      sp1, hi2, lo2, u2, c2, buf2, 64, 128);
  lif_scan<64, false, true><<<(BATCH * 64) / 64, 64, 0, stream>>>(buf2, nullptr, tsum);

  finalize<<<1, 64, 0, stream>>>(tsum, Wc, bc, out);
}

// Round 6
// 135.405 us; speedup vs baseline: 1.4131x; 1.0427x over previous
//
#include <hip/hip_runtime.h>

#define T_STEPS 512
#define BATCH 64

// fp32 casts of np.exp(-1/20), np.exp(-1/5)
__device__ constexpr float ALPHA_ = 0.95122942450071400910f;
__device__ constexpr float BETA_  = 0.81873075307798185867f;

typedef __attribute__((ext_vector_type(8))) short bf16x8;
typedef __attribute__((ext_vector_type(4))) float f32x4;

__device__ inline unsigned short f2bf_rne(float f) {
  union { float f; unsigned int u; } v{f};
  const unsigned int u = v.u;
  return (unsigned short)((u + 0x7FFFu + ((u >> 16) & 1u)) >> 16);
}
__device__ inline float bf2f(unsigned short h) {
  union { unsigned int u; float f; } v{(unsigned int)h << 16};
  return v.f;
}

__device__ inline void gload16(const void* g, void* l) {
  __builtin_amdgcn_global_load_lds(
      (const __attribute__((address_space(1))) unsigned int*)g,
      (__attribute__((address_space(3))) unsigned int*)l, 16, 0, 0);
}

// pack trunc-bf16(first) | trunc-bf16(second)<<16  (exact for spike 0/1)
__device__ inline unsigned int pkbf(float first, float second) {
#if __has_builtin(__builtin_amdgcn_perm)
  return __builtin_amdgcn_perm(__float_as_uint(second), __float_as_uint(first),
                               0x07060302u);
#else
  return (__float_as_uint(first) >> 16) | (__float_as_uint(second) & 0xFFFF0000u);
#endif
}

// 8 fp32 (lo = k0..3, hi = k4..7) -> MFMA bf16x8 fragment word order
__device__ inline bf16x8 cvt_frag(const f32x4 lo, const f32x4 hi) {
  union { unsigned int w[4]; bf16x8 v; } u;
  u.w[0] = pkbf(lo.x, lo.y);
  u.w[1] = pkbf(lo.z, lo.w);
  u.w[2] = pkbf(hi.x, hi.y);
  u.w[3] = pkbf(hi.z, hi.w);
  return u.v;
}

// ---------------------------------------------------------------------------
// Fire-and-forget double-buffered MFMA GEMM:
//   ALL staging via global_load_lds (A fp32 two-half frag-linear; B hi/lo
//   frag-linear from prep_split). Zero ds_writes, zero register staging.
//   Per K-step: stage(kb+1) -> ds_read(kb)+MFMA -> s_waitcnt vmcnt(0) +
//   raw s_barrier + sched_barrier. Loads age a full compute phase before wait.
// Waves: WM x WC wave tiles of TM x 64. BM=WM*TM, BN=WC*64, 256 threads.
// A_F32: A fp32 in LDS as [frag_row][2 halves][64 lanes][16B]; frag read =
//   2x ds_read_b128 + v_perm truncation (exact for 0/1 spikes).
// LNFOLD: rowsum via ones-MFMA; epilogue inv[r]*acc - mi[r]*u[c] + c[c].
// ---------------------------------------------------------------------------
template <int WM, int WC, int TM, bool A_F32, bool LNFOLD>
__global__ __launch_bounds__(256) void gemm_pipe(
    const void* __restrict__ Av, const char* __restrict__ Bhi,
    const char* __restrict__ Blo, const float* __restrict__ uvec,
    const float* __restrict__ cvec, float* __restrict__ C, int N, int K) {
  constexpr int BM = WM * TM;
  constexpr int BN = WC * 64;
  constexpr int FM = TM / 16;                      // m-frags per wave
  constexpr int ABY = A_F32 ? BM * 128 : BM * 64;  // A bytes per K-step
  constexpr int BBH = BN * 64;                     // B bytes per half
  constexpr int BUFBY = ABY + 2 * BBH;
  constexpr int API = (ABY / 16) / 256;            // A gloads per thread
  __shared__ char smem[2 * BUFBY];

  const int tid = threadIdx.x;
  const int lane = tid & 63;
  const int wave = tid >> 6;
  const int wm = wave / WC, wc = wave % WC;
  const int l15 = lane & 15, l4 = lane >> 4;
  const int row0 = blockIdx.y * BM;
  const int col0 = blockIdx.x * BN;
  const int KB = K / 32;

  const char* Ab = (const char*)Av;

  // per-thread global source addresses (kb=0); step strides added in stage()
  const char* a_src[API];
#pragma unroll
  for (int i = 0; i < API; ++i) {
    const int unit = i * 256 + tid;
    if constexpr (A_F32) {
      const int fr = unit >> 7, h = (unit >> 6) & 1, ln = unit & 63;
      a_src[i] = Ab + ((size_t)(row0 + fr * 16 + (ln & 15)) * K + ((ln >> 4) * 8)) * 4 + h * 16;
    } else {
      const int r = ((unit >> 6) << 4) | (unit & 15);
      const int j = (unit >> 4) & 3;
      a_src[i] = Ab + ((size_t)(row0 + r) * K + j * 8) * 2;
    }
  }
  const char* bh_src[WC];
  const char* bl_src[WC];
#pragma unroll
  for (int g = 0; g < WC; ++g) {
    const size_t so = ((size_t)(blockIdx.x * WC + g) * KB) * 4096 + (size_t)tid * 16;
    bh_src[g] = Bhi + so;
    bl_src[g] = Blo + so;
  }

  auto stage = [&](int kb, char* buf) {
#pragma unroll
    for (int i = 0; i < API; ++i) {
      const int unit = i * 256 + tid;
      gload16(a_src[i] + (size_t)kb * (A_F32 ? 128 : 64), buf + unit * 16);
    }
#pragma unroll
    for (int g = 0; g < WC; ++g) {
      gload16(bh_src[g] + (size_t)kb * 4096, buf + ABY + (g * 256 + tid) * 16);
      gload16(bl_src[g] + (size_t)kb * 4096, buf + ABY + BBH + (g * 256 + tid) * 16);
    }
  };

  f32x4 acc[FM][4] = {};
  f32x4 acc1[FM] = {};
  const bf16x8 ONES = {0x3F80, 0x3F80, 0x3F80, 0x3F80,
                       0x3F80, 0x3F80, 0x3F80, 0x3F80};

  // ---- prologue ----
  stage(0, smem);
  asm volatile("s_waitcnt vmcnt(0)" ::: "memory");
  __builtin_amdgcn_s_barrier();
  __builtin_amdgcn_sched_barrier(0);

  for (int kb = 0; kb < KB; ++kb) {
    char* bufc = smem + (kb & 1) * BUFBY;
    char* bufn = smem + ((kb & 1) ^ 1) * BUFBY;
    if (kb + 1 < KB) stage(kb + 1, bufn);

    bf16x8 af[FM], bh[4], bl[4];
#pragma unroll
    for (int m = 0; m < FM; ++m) {
      const int fr = wm * FM + m;
      if constexpr (A_F32) {
        const f32x4 lo = *(const f32x4*)(bufc + ((fr * 2 + 0) * 64 + lane) * 16);
        const f32x4 hi = *(const f32x4*)(bufc + ((fr * 2 + 1) * 64 + lane) * 16);
        af[m] = cvt_frag(lo, hi);
      } else {
        af[m] = *(const bf16x8*)(bufc + (fr * 64 + lane) * 16);
      }
    }
#pragma unroll
    for (int n = 0; n < 4; ++n) {
      bh[n] = *(const bf16x8*)(bufc + ABY + (wc * 256 + n * 64 + lane) * 16);
      bl[n] = *(const bf16x8*)(bufc + ABY + BBH + (wc * 256 + n * 64 + lane) * 16);
    }

#pragma unroll
    for (int m = 0; m < FM; ++m) {
#pragma unroll
      for (int n = 0; n < 4; ++n) {
        acc[m][n] = __builtin_amdgcn_mfma_f32_16x16x32_bf16(af[m], bh[n], acc[m][n], 0, 0, 0);
        acc[m][n] = __builtin_amdgcn_mfma_f32_16x16x32_bf16(af[m], bl[n], acc[m][n], 0, 0, 0);
      }
      if constexpr (LNFOLD)
        acc1[m] = __builtin_amdgcn_mfma_f32_16x16x32_bf16(af[m], ONES, acc1[m], 0, 0, 0);
    }

    asm volatile("s_waitcnt vmcnt(0)" ::: "memory");
    __builtin_amdgcn_s_barrier();
    __builtin_amdgcn_sched_barrier(0);
  }

  // ---- epilogue ----
  const int row0w = row0 + wm * TM;
  const int col0w = col0 + wc * 64;
#pragma unroll
  for (int m = 0; m < FM; ++m) {
    const int rbase = row0w + m * 16 + l4 * 4;
    float iv[4], mv[4];
    if constexpr (LNFOLD) {
#pragma unroll
      for (int r = 0; r < 4; ++r) {
        const float mean = acc1[m][r] / (float)K;
        const float inv = 1.0f / sqrtf(mean * (1.f - mean) + 1e-6f);
        iv[r] = inv;
        mv[r] = mean * inv;
      }
    }
#pragma unroll
    for (int n = 0; n < 4; ++n) {
      const int c = col0w + n * 16 + l15;
      const float cc = cvec[c];
      float uu = 0.f;
      if constexpr (LNFOLD) uu = uvec[c];
#pragma unroll
      for (int r = 0; r < 4; ++r) {
        float v;
        if constexpr (LNFOLD) v = iv[r] * acc[m][n][r] - mv[r] * uu + cc;
        else v = acc[m][n][r] + cc;
        C[(size_t)(rbase + r) * N + c] = v;
      }
    }
  }
}

// ---------------------------------------------------------------------------
// Prep: W[K,N] f32 (optionally scaled by s[k]) -> split hi/lo bf16 in the
// fragment-linear (64-col-block) global layout consumed by gemm_pipe.
// ---------------------------------------------------------------------------
__global__ void prep_split(const float* __restrict__ W, const float* __restrict__ s,
                           char* __restrict__ hi, char* __restrict__ lo,
                           int K, int N) {
  const int g = blockIdx.x * 256 + threadIdx.x;
  const int total = (K * N) / 8;
  if (g >= total) return;
  constexpr int UB = 256;  // units per (col-block, K-step)
  const int KB = K / 32;
  const int unit = g % UB;
  const int kb = (g / UB) % KB;
  const int cb = g / (UB * KB);
  const int n = cb * 64 + ((unit >> 6) << 4) + (unit & 15);
  const int kbase = kb * 32 + ((unit >> 4) & 3) * 8;
  short h8[8], l8[8];
#pragma unroll
  for (int jj = 0; jj < 8; ++jj) {
    const int k = kbase + jj;
    float w = W[(size_t)k * N + n];
    if (s) w *= s[k];
    const unsigned short hb = f2bf_rne(w);
    const unsigned short lb = f2bf_rne(w - bf2f(hb));
    h8[jj] = (short)hb;
    l8[jj] = (short)lb;
  }
  *(bf16x8*)(hi + (size_t)g * 16) = *(const bf16x8*)h8;
  *(bf16x8*)(lo + (size_t)g * 16) = *(const bf16x8*)l8;
}

// u[n] = sum_k s[k]*W[k,n];  c[n] = sum_k b[k]*W[k,n] + bias2[n]. Block per n.
__global__ __launch_bounds__(256) void prep_consts(
    const float* __restrict__ W, const float* __restrict__ s,
    const float* __restrict__ b, const float* __restrict__ bias2,
    float* __restrict__ u, float* __restrict__ c, int K, int N) {
  const int n = blockIdx.x;
  const int t = threadIdx.x;
  float us = 0.f, cs = 0.f;
  for (int k = t; k < K; k += 256) {
    const float w = W[(size_t)k * N + n];
    us += s[k] * w;
    cs += b[k] * w;
  }
  __shared__ float su[256], sc[256];
  su[t] = us;
  sc[t] = cs;
  __syncthreads();
  for (int o = 128; o > 0; o >>= 1) {
    if (t < o) { su[t] += su[t + o]; sc[t] += sc[t + o]; }
    __syncthreads();
  }
  if (t == 0) { u[n] = su[0]; c[n] = sc[0] + bias2[n]; }
}

// ---------------------------------------------------------------------------
// LIF scan over T, one thread per (b,h); reads fp32 currents, writes bf16
// spikes (exact) and/or per-(b,h) spike counts. 32x unrolled loads.
// ---------------------------------------------------------------------------
template <int H, bool SPIKE_OUT, bool ACCUM>
__global__ void lif_scan(const float* __restrict__ xt,
                         unsigned short* __restrict__ sp,
                         float* __restrict__ tsum) {
  const int n = blockIdx.x * 64 + threadIdx.x;
  const int b = n / H, h = n % H;
  const float* p = xt + (size_t)b * T_STEPS * H + h;
  unsigned short* q = nullptr;
  if constexpr (SPIKE_OUT) q = sp + (size_t)b * T_STEPS * H + h;

  float v = 0.f, cur = 0.f, ts = 0.f;
  for (int t = 0; t < T_STEPS; t += 32) {
    float x[32];
#pragma unroll
    for (int u = 0; u < 32; ++u) x[u] = p[(size_t)u * H];
#pragma unroll
    for (int u = 0; u < 32; ++u) {
      cur = BETA_ * cur + x[u];
      v = ALPHA_ * v + cur;
      const bool sb = (v >= 1.f);
      if constexpr (SPIKE_OUT) q[(size_t)u * H] = sb ? 0x3F80 : 0;
      if constexpr (ACCUM) ts += sb ? 1.f : 0.f;
      v = sb ? 0.f : v;
    }
    p += (size_t)32 * H;
    if constexpr (SPIKE_OUT) q += (size_t)32 * H;
  }
  if constexpr (ACCUM) tsum[n] = ts;
}

__global__ void finalize(const float* __restrict__ tsum,
                         const float* __restrict__ Wc,
                         const float* __restrict__ bc,
                         float* __restrict__ out) {
  const int b = threadIdx.x;  // 64 threads, one wave
  float s = 0.f;
#pragma unroll 8
  for (int h = 0; h < 64; ++h) s += tsum[b * 64 + h];
  const float pooled = s * (1.0f / (512.f * 64.f));
  out[2 + b] = pooled;

  float tot = pooled;
  float l0 = pooled * Wc[b * 2 + 0];
  float l1 = pooled * Wc[b * 2 + 1];
#pragma unroll
  for (int off = 32; off > 0; off >>= 1) {
    tot += __shfl_xor(tot, off);
    l0 += __shfl_xor(l0, off);
    l1 += __shfl_xor(l1, off);
  }
  if (b == 0) {
    out[0] = l0 + bc[0];
    out[1] = l1 + bc[1];
    out[66] = tot * (1.0f / 64.f);
  }
}

extern "C" void kernel_launch(void* const* d_in, const int* in_sizes, int n_in,
                              void* d_out, int out_size, void* d_ws, size_t ws_size,
                              hipStream_t stream) {
  const float* X    = (const float*)d_in[0];   // [64,512,64,16] -> [32768,1024]
  const float* W0   = (const float*)d_in[1];   // [1024,256]
  const float* b0   = (const float*)d_in[2];
  const float* W1   = (const float*)d_in[3];   // [256,128]
  const float* b1   = (const float*)d_in[4];
  const float* W2   = (const float*)d_in[5];   // [128,64]
  const float* b2   = (const float*)d_in[6];
  const float* ln1s = (const float*)d_in[7];
  const float* ln1b = (const float*)d_in[8];
  const float* ln2s = (const float*)d_in[9];
  const float* ln2b = (const float*)d_in[10];
  const float* Wc   = (const float*)d_in[11];  // [64,2]
  const float* bc   = (const float*)d_in[12];
  float* out = (float*)d_out;

  char* w = (char*)d_ws;
  float* buf0 = (float*)w;                       // [32768,256] f32 = 33554432 B
  float* buf1 = (float*)w;                       // alias: buf0 dead after scan0
  float* buf2 = (float*)(w + 16777216);          // [32768,64] f32, after buf1
  size_t off = 33554432;
  unsigned short* sp0 = (unsigned short*)(w + off); off += 16777216;  // [32768,256] bf16
  unsigned short* sp1 = (unsigned short*)(w + off); off += 8388608;   // [32768,128] bf16
  char* hi0 = w + off; off += 524288;
  char* lo0 = w + off; off += 524288;
  char* hi1 = w + off; off += 65536;
  char* lo1 = w + off; off += 65536;
  char* hi2 = w + off; off += 16384;
  char* lo2 = w + off; off += 16384;
  float* u1 = (float*)(w + off); off += 512;
  float* c1 = (float*)(w + off); off += 512;
  float* u2 = (float*)(w + off); off += 256;
  float* c2 = (float*)(w + off); off += 256;
  float* tsum = (float*)(w + off); off += 16384;

  const int M = 32768;

  // --- weight prep (frag-linear 64-col-block split hi/lo + LN-fold consts) ---
  prep_split<<<128, 256, 0, stream>>>(W0, nullptr, hi0, lo0, 1024, 256);
  prep_split<<<16, 256, 0, stream>>>(W1, ln1s, hi1, lo1, 256, 128);
  prep_split<<<4, 256, 0, stream>>>(W2, ln2s, hi2, lo2, 128, 64);
  prep_consts<<<128, 256, 0, stream>>>(W1, ln1s, ln1b, b1, u1, c1, 256, 128);
  prep_consts<<<64, 256, 0, stream>>>(W2, ln2s, ln2b, b2, u2, c2, 128, 64);

  // --- layer 0: xt = X @ W0 + b0 (2x2 waves, 64x64 tiles, BM=BN=128) ---
  gemm_pipe<2, 2, 64, true, false><<<dim3(2, M / 128), 256, 0, stream>>>(
      X, hi0, lo0, nullptr, b0, buf0, 256, 1024);
  lif_scan<256, true, false><<<(BATCH * 256) / 64, 64, 0, stream>>>(buf0, sp0, nullptr);

  // --- layer 1: LN folded (rowsum via ones-MFMA), BM=128, BN=64 ---
  gemm_pipe<4, 1, 32, false, true><<<dim3(2, M / 128), 256, 0, stream>>>(
      sp0, hi1, lo1, u1, c1, buf1, 128, 256);
  lif_scan<128, true, false><<<(BATCH * 128) / 64, 64, 0, stream>>>(buf1, sp1, nullptr);

  // --- layer 2 ---
  gemm_pipe<4, 1, 32, false, true><<<dim3(1, M / 128), 256, 0, stream>>>(
      sp1, hi2, lo2, u2, c2, buf2, 64, 128);
  lif_scan<64, false, true><<<(BATCH * 64) / 64, 64, 0, stream>>>(buf2, nullptr, tsum);

  finalize<<<1, 64, 0, stream>>>(tsum, Wc, bc, out);
}

// Round 8
// 132.144 us; speedup vs baseline: 1.4480x; 1.0247x over previous
//
#include <hip/hip_runtime.h>

#define T_STEPS 512
#define BATCH 64

// fp32 casts of np.exp(-1/20), np.exp(-1/5)
__device__ constexpr float ALPHA_ = 0.95122942450071400910f;
__device__ constexpr float BETA_  = 0.81873075307798185867f;

typedef __attribute__((ext_vector_type(8))) short bf16x8;
typedef __attribute__((ext_vector_type(4))) float f32x4;

__device__ inline unsigned short f2bf_rne(float f) {
  union { float f; unsigned int u; } v{f};
  const unsigned int u = v.u;
  return (unsigned short)((u + 0x7FFFu + ((u >> 16) & 1u)) >> 16);
}
__device__ inline float bf2f(unsigned short h) {
  union { unsigned int u; float f; } v{(unsigned int)h << 16};
  return v.f;
}

__device__ inline void gload16(const void* g, void* l) {
  __builtin_amdgcn_global_load_lds(
      (const __attribute__((address_space(1))) unsigned int*)g,
      (__attribute__((address_space(3))) unsigned int*)l, 16, 0, 0);
}

// pack trunc-bf16(first) | trunc-bf16(second)<<16  (exact for spike 0/1)
__device__ inline unsigned int pkbf(float first, float second) {
#if __has_builtin(__builtin_amdgcn_perm)
  return __builtin_amdgcn_perm(__float_as_uint(second), __float_as_uint(first),
                               0x07060302u);
#else
  return (__float_as_uint(first) >> 16) | (__float_as_uint(second) & 0xFFFF0000u);
#endif
}

// 8 fp32 (lo = k0..3, hi = k4..7) -> MFMA bf16x8 fragment word order
__device__ inline bf16x8 cvt_frag(const f32x4 lo, const f32x4 hi) {
  union { unsigned int w[4]; bf16x8 v; } u;
  u.w[0] = pkbf(lo.x, lo.y);
  u.w[1] = pkbf(lo.z, lo.w);
  u.w[2] = pkbf(hi.x, hi.y);
  u.w[3] = pkbf(hi.z, hi.w);
  return u.v;
}

// ---------------------------------------------------------------------------
// Deep-pipelined MFMA GEMM, depth-2 prefetch:
//   A: global_load_lds into TRIPLE-buffered frag-linear LDS (AIP instr/thread
//      per step, issued for kb+2). The gload_lds -> ds_read dependency is the
//      ONLY compiler-invisible one; it is protected by a hand-counted
//      s_waitcnt vmcnt(AIP+16) before the raw s_barrier:
//      outstanding there = [A(kb+1) AIP][B(kb+1) 8][A(kb+2) AIP][B(kb+2) 8]
//      -> completes exactly A(kb+1), which the next iteration reads.
//   B: frag-linear hi/lo bf16 in global (L2-resident), loaded as PLAIN C++
//      loads into statically-named ping-pong register sets (bh0/bh1), issued
//      for kb+2 right after the set's last consumer. The compiler owns this
//      dependency and inserts exact waits (it sees all VMEM ops incl. the
//      gload_lds builtins). No asm-defined registers anywhere (R7 bug fix).
//   K is a RUNTIME arg -> loop not fully unrolled -> per-iteration VMEM
//   instruction counts are constant (clamped tail addresses re-load last
//   tile; harmless dups). sched_barrier(0) pins region order.
// Waves: WM x WC wave tiles of TM x 64 (BM = WM*TM, BN = WC*64), 256 thr.
// LNFOLD: rowsum via ones-MFMA; epilogue inv[r]*acc - mi[r]*u[c] + c[c].
// ---------------------------------------------------------------------------
template <int WM, int WC, int TM, bool A_F32, bool LNFOLD>
__global__ __launch_bounds__(256) void gemm_deep2(
    const void* __restrict__ Av, const char* __restrict__ Bhi,
    const char* __restrict__ Blo, const float* __restrict__ uvec,
    const float* __restrict__ cvec, float* __restrict__ C, int N, int K) {
  constexpr int BM = WM * TM;
  constexpr int FM = TM / 16;                      // m-frags per wave
  constexpr int ABY = A_F32 ? BM * 128 : BM * 64;  // A bytes per K-step
  constexpr int AIP = ABY / 4096;                  // A gloads per thread
  constexpr int ASTEP = A_F32 ? 128 : 64;          // A source bytes per kb
  constexpr int W2N = AIP + 16;                    // completes A(kb+1)
  __shared__ char smem[3 * ABY];

  const int tid = threadIdx.x;
  const int lane = tid & 63;
  const int wave = tid >> 6;
  const int wm = wave / WC, wc = wave % WC;
  const int l15 = lane & 15, l4 = lane >> 4;
  const int row0 = blockIdx.y * BM;
  const int col0 = blockIdx.x * (WC * 64);
  const int KB = K / 32;

  const char* Ab = (const char*)Av;

  // per-thread A global source (kb-independent part)
  const char* a_src[AIP];
#pragma unroll
  for (int i = 0; i < AIP; ++i) {
    const int unit = i * 256 + tid;
    if constexpr (A_F32) {
      const int fr = unit >> 7, h = (unit >> 6) & 1, ln = unit & 63;
      a_src[i] = Ab + ((size_t)(row0 + fr * 16 + (ln & 15)) * K + ((ln >> 4) * 8)) * 4 + h * 16;
    } else {
      const int r = ((unit >> 6) << 4) | (unit & 15);
      const int j = (unit >> 4) & 3;
      a_src[i] = Ab + ((size_t)(row0 + r) * K + j * 8) * 2;
    }
  }
  // per-lane B base (frag-linear: col-block stride KB*4096, step stride 4096)
  const char* bh_base = Bhi + (size_t)(blockIdx.x * WC + wc) * KB * 4096 + (size_t)lane * 16;
  const char* bl_base = Blo + (size_t)(blockIdx.x * WC + wc) * KB * 4096 + (size_t)lane * 16;

  int aoff = 0, boff = 0;
  const int amax = (KB - 1) * ASTEP;
  const int bmax = (KB - 1) * 4096;

  f32x4 acc[FM][4] = {};
  f32x4 acc1[FM] = {};
  const bf16x8 ONES = {0x3F80, 0x3F80, 0x3F80, 0x3F80,
                       0x3F80, 0x3F80, 0x3F80, 0x3F80};
  bf16x8 bh0[4], bl0[4], bh1[4], bl1[4];

#define SB __builtin_amdgcn_sched_barrier(0)

#define STAGE_A(buf)                                                   \
  do {                                                                 \
    _Pragma("unroll") for (int i = 0; i < AIP; ++i)                    \
        gload16(a_src[i] + aoff, (buf) + (i * 256 + tid) * 16);        \
  } while (0)

#define LOAD_B(bh, bl, off_)                                           \
  do {                                                                 \
    const char* ph = bh_base + (off_);                                 \
    const char* pl = bl_base + (off_);                                 \
    bh[0] = *(const bf16x8*)(ph);                                      \
    bh[1] = *(const bf16x8*)(ph + 1024);                               \
    bh[2] = *(const bf16x8*)(ph + 2048);                               \
    bh[3] = *(const bf16x8*)(ph + 3072);                               \
    bl[0] = *(const bf16x8*)(pl);                                      \
    bl[1] = *(const bf16x8*)(pl + 1024);                               \
    bl[2] = *(const bf16x8*)(pl + 2048);                               \
    bl[3] = *(const bf16x8*)(pl + 3072);                               \
  } while (0)

  // ---- prologue: queue = [A0][B0][A1][B1]; wait completes A0; barrier ----
  char* bufR = smem;
  char* bufM = smem + ABY;
  char* bufS = smem + 2 * ABY;

  SB;
  STAGE_A(bufR);                      // A(0)
  SB;
  LOAD_B(bh0, bl0, 0);                // B(0)
  SB;
  aoff = ASTEP;
  STAGE_A(bufM);                      // A(1)
  SB;
  LOAD_B(bh1, bl1, 4096);             // B(1)  (KB >= 4 for all layers)
  SB;
  aoff = (2 * ASTEP < amax) ? 2 * ASTEP : amax;
  boff = (2 * 4096 < bmax) ? 2 * 4096 : bmax;
  asm volatile("s_waitcnt vmcnt(%0)" ::"i"(W2N) : "memory");  // A(0) landed
  __builtin_amdgcn_s_barrier();
  SB;

#define KSTEP(BH, BL)                                                        \
  do {                                                                       \
    STAGE_A(bufS); /* A(kb+2) */                                             \
    aoff = (aoff < amax) ? aoff + ASTEP : aoff;                              \
    SB;                                                                      \
    bf16x8 af[FM];                                                           \
    _Pragma("unroll") for (int m = 0; m < FM; ++m) {                         \
      const int fr = wm * FM + m;                                            \
      if constexpr (A_F32) {                                                 \
        const f32x4 lo = *(const f32x4*)(bufR + ((fr * 2 + 0) * 64 + lane) * 16); \
        const f32x4 hi = *(const f32x4*)(bufR + ((fr * 2 + 1) * 64 + lane) * 16); \
        af[m] = cvt_frag(lo, hi);                                            \
      } else {                                                               \
        af[m] = *(const bf16x8*)(bufR + (fr * 64 + lane) * 16);              \
      }                                                                      \
    }                                                                        \
    SB;                                                                      \
    _Pragma("unroll") for (int m = 0; m < FM; ++m) {                         \
      _Pragma("unroll") for (int n = 0; n < 4; ++n) {                        \
        acc[m][n] = __builtin_amdgcn_mfma_f32_16x16x32_bf16(af[m], BH[n],    \
                                                            acc[m][n], 0, 0, 0); \
        acc[m][n] = __builtin_amdgcn_mfma_f32_16x16x32_bf16(af[m], BL[n],    \
                                                            acc[m][n], 0, 0, 0); \
      }                                                                      \
      if constexpr (LNFOLD)                                                  \
        acc1[m] = __builtin_amdgcn_mfma_f32_16x16x32_bf16(af[m], ONES,       \
                                                          acc1[m], 0, 0, 0); \
    }                                                                        \
    SB;                                                                      \
    LOAD_B(BH, BL, boff); /* B(kb+2) into the set just consumed */           \
    boff = (boff < bmax) ? boff + 4096 : boff;                               \
    SB;                                                                      \
    asm volatile("s_waitcnt vmcnt(%0)" ::"i"(W2N) : "memory");               \
    __builtin_amdgcn_s_barrier();                                            \
    SB;                                                                      \
    { char* t = bufR; bufR = bufM; bufM = bufS; bufS = t; }                  \
  } while (0)

  const int ITER = KB / 2;  // KB even for all layers (32 / 8 / 4)
  for (int it = 0; it < ITER; ++it) {
    KSTEP(bh0, bl0);   // even kb
    KSTEP(bh1, bl1);   // odd  kb
  }
  asm volatile("s_waitcnt vmcnt(0) lgkmcnt(0)" ::: "memory");

#undef KSTEP
#undef LOAD_B
#undef STAGE_A
#undef SB

  // ---- epilogue ----
  const int row0w = row0 + wm * TM;
  const int col0w = col0 + wc * 64;
#pragma unroll
  for (int m = 0; m < FM; ++m) {
    const int rbase = row0w + m * 16 + l4 * 4;
    float iv[4], mv[4];
    if constexpr (LNFOLD) {
#pragma unroll
      for (int r = 0; r < 4; ++r) {
        const float mean = acc1[m][r] / (float)K;
        const float inv = 1.0f / sqrtf(mean * (1.f - mean) + 1e-6f);
        iv[r] = inv;
        mv[r] = mean * inv;
      }
    }
#pragma unroll
    for (int n = 0; n < 4; ++n) {
      const int c = col0w + n * 16 + l15;
      const float cc = cvec[c];
      float uu = 0.f;
      if constexpr (LNFOLD) uu = uvec[c];
#pragma unroll
      for (int r = 0; r < 4; ++r) {
        float v;
        if constexpr (LNFOLD) v = iv[r] * acc[m][n][r] - mv[r] * uu + cc;
        else v = acc[m][n][r] + cc;
        C[(size_t)(rbase + r) * N + c] = v;
      }
    }
  }
}

// ---------------------------------------------------------------------------
// Prep: W[K,N] f32 (optionally scaled by s[k]) -> split hi/lo bf16 in the
// fragment-linear (64-col-block) global layout consumed by gemm_deep2.
// ---------------------------------------------------------------------------
__global__ void prep_split(const float* __restrict__ W, const float* __restrict__ s,
                           char* __restrict__ hi, char* __restrict__ lo,
                           int K, int N) {
  const int g = blockIdx.x * 256 + threadIdx.x;
  const int total = (K * N) / 8;
  if (g >= total) return;
  constexpr int UB = 256;  // units per (col-block, K-step)
  const int KB = K / 32;
  const int unit = g % UB;
  const int kb = (g / UB) % KB;
  const int cb = g / (UB * KB);
  const int n = cb * 64 + ((unit >> 6) << 4) + (unit & 15);
  const int kbase = kb * 32 + ((unit >> 4) & 3) * 8;
  short h8[8], l8[8];
#pragma unroll
  for (int jj = 0; jj < 8; ++jj) {
    const int k = kbase + jj;
    float w = W[(size_t)k * N + n];
    if (s) w *= s[k];
    const unsigned short hb = f2bf_rne(w);
    const unsigned short lb = f2bf_rne(w - bf2f(hb));
    h8[jj] = (short)hb;
    l8[jj] = (short)lb;
  }
  *(bf16x8*)(hi + (size_t)g * 16) = *(const bf16x8*)h8;
  *(bf16x8*)(lo + (size_t)g * 16) = *(const bf16x8*)l8;
}

// u[n] = sum_k s[k]*W[k,n];  c[n] = sum_k b[k]*W[k,n] + bias2[n]. Block per n.
__global__ __launch_bounds__(256) void prep_consts(
    const float* __restrict__ W, const float* __restrict__ s,
    const float* __restrict__ b, const float* __restrict__ bias2,
    float* __restrict__ u, float* __restrict__ c, int K, int N) {
  const int n = blockIdx.x;
  const int t = threadIdx.x;
  float us = 0.f, cs = 0.f;
  for (int k = t; k < K; k += 256) {
    const float w = W[(size_t)k * N + n];
    us += s[k] * w;
    cs += b[k] * w;
  }
  __shared__ float su[256], sc[256];
  su[t] = us;
  sc[t] = cs;
  __syncthreads();
  for (int o = 128; o > 0; o >>= 1) {
    if (t < o) { su[t] += su[t + o]; sc[t] += sc[t + o]; }
    __syncthreads();
  }
  if (t == 0) { u[n] = su[0]; c[n] = sc[0] + bias2[n]; }
}

// ---------------------------------------------------------------------------
// LIF scan over T, one thread per (b,h); reads fp32 currents, writes bf16
// spikes (exact) and/or per-(b,h) spike counts. 32x unrolled loads.
// ---------------------------------------------------------------------------
template <int H, bool SPIKE_OUT, bool ACCUM>
__global__ void lif_scan(const float* __restrict__ xt,
                         unsigned short* __restrict__ sp,
                         float* __restrict__ tsum) {
  const int n = blockIdx.x * 64 + threadIdx.x;
  const int b = n / H, h = n % H;
  const float* p = xt + (size_t)b * T_STEPS * H + h;
  unsigned short* q = nullptr;
  if constexpr (SPIKE_OUT) q = sp + (size_t)b * T_STEPS * H + h;

  float v = 0.f, cur = 0.f, ts = 0.f;
  for (int t = 0; t < T_STEPS; t += 32) {
    float x[32];
#pragma unroll
    for (int u = 0; u < 32; ++u) x[u] = p[(size_t)u * H];
#pragma unroll
    for (int u = 0; u < 32; ++u) {
      cur = BETA_ * cur + x[u];
      v = ALPHA_ * v + cur;
      const bool sb = (v >= 1.f);
      if constexpr (SPIKE_OUT) q[(size_t)u * H] = sb ? 0x3F80 : 0;
      if constexpr (ACCUM) ts += sb ? 1.f : 0.f;
      v = sb ? 0.f : v;
    }
    p += (size_t)32 * H;
    if constexpr (SPIKE_OUT) q += (size_t)32 * H;
  }
  if constexpr (ACCUM) tsum[n] = ts;
}

__global__ void finalize(const float* __restrict__ tsum,
                         const float* __restrict__ Wc,
                         const float* __restrict__ bc,
                         float* __restrict__ out) {
  const int b = threadIdx.x;  // 64 threads, one wave
  float s = 0.f;
#pragma unroll 8
  for (int h = 0; h < 64; ++h) s += tsum[b * 64 + h];
  const float pooled = s * (1.0f / (512.f * 64.f));
  out[2 + b] = pooled;

  float tot = pooled;
  float l0 = pooled * Wc[b * 2 + 0];
  float l1 = pooled * Wc[b * 2 + 1];
#pragma unroll
  for (int off = 32; off > 0; off >>= 1) {
    tot += __shfl_xor(tot, off);
    l0 += __shfl_xor(l0, off);
    l1 += __shfl_xor(l1, off);
  }
  if (b == 0) {
    out[0] = l0 + bc[0];
    out[1] = l1 + bc[1];
    out[66] = tot * (1.0f / 64.f);
  }
}

extern "C" void kernel_launch(void* const* d_in, const int* in_sizes, int n_in,
                              void* d_out, int out_size, void* d_ws, size_t ws_size,
                              hipStream_t stream) {
  const float* X    = (const float*)d_in[0];   // [64,512,64,16] -> [32768,1024]
  const float* W0   = (const float*)d_in[1];   // [1024,256]
  const float* b0   = (const float*)d_in[2];
  const float* W1   = (const float*)d_in[3];   // [256,128]
  const float* b1   = (const float*)d_in[4];
  const float* W2   = (const float*)d_in[5];   // [128,64]
  const float* b2   = (const float*)d_in[6];
  const float* ln1s = (const float*)d_in[7];
  const float* ln1b = (const float*)d_in[8];
  const float* ln2s = (const float*)d_in[9];
  const float* ln2b = (const float*)d_in[10];
  const float* Wc   = (const float*)d_in[11];  // [64,2]
  const float* bc   = (const float*)d_in[12];
  float* out = (float*)d_out;

  char* w = (char*)d_ws;
  float* buf0 = (float*)w;                       // [32768,256] f32 = 33554432 B
  float* buf1 = (float*)w;                       // alias: buf0 dead after scan0
  float* buf2 = (float*)(w + 16777216);          // [32768,64] f32, after buf1
  size_t off = 33554432;
  unsigned short* sp0 = (unsigned short*)(w + off); off += 16777216;  // [32768,256] bf16
  unsigned short* sp1 = (unsigned short*)(w + off); off += 8388608;   // [32768,128] bf16
  char* hi0 = w + off; off += 524288;
  char* lo0 = w + off; off += 524288;
  char* hi1 = w + off; off += 65536;
  char* lo1 = w + off; off += 65536;
  char* hi2 = w + off; off += 16384;
  char* lo2 = w + off; off += 16384;
  float* u1 = (float*)(w + off); off += 512;
  float* c1 = (float*)(w + off); off += 512;
  float* u2 = (float*)(w + off); off += 256;
  float* c2 = (float*)(w + off); off += 256;
  float* tsum = (float*)(w + off); off += 16384;

  const int M = 32768;

  // --- weight prep (frag-linear 64-col-block split hi/lo + LN-fold consts) ---
  prep_split<<<128, 256, 0, stream>>>(W0, nullptr, hi0, lo0, 1024, 256);
  prep_split<<<16, 256, 0, stream>>>(W1, ln1s, hi1, lo1, 256, 128);
  prep_split<<<4, 256, 0, stream>>>(W2, ln2s, hi2, lo2, 128, 64);
  prep_consts<<<128, 256, 0, stream>>>(W1, ln1s, ln1b, b1, u1, c1, 256, 128);
  prep_consts<<<64, 256, 0, stream>>>(W2, ln2s, ln2b, b2, u2, c2, 128, 64);

  // --- layer 0: xt = X @ W0 + b0. BM=64, BN=256 (A read once; 4 col-waves),
  //     A fp32 gload_lds triple-buffer, B in compiler-managed regs. ---
  gemm_deep2<1, 4, 64, true, false><<<dim3(1, M / 64), 256, 0, stream>>>(
      X, hi0, lo0, nullptr, b0, buf0, 256, 1024);
  lif_scan<256, true, false><<<(BATCH * 256) / 64, 64, 0, stream>>>(buf0, sp0, nullptr);

  // --- layer 1: LN folded (rowsum via ones-MFMA). BM=64, BN=128. ---
  gemm_deep2<2, 2, 32, false, true><<<dim3(1, M / 64), 256, 0, stream>>>(
      sp0, hi1, lo1, u1, c1, buf1, 128, 256);
  lif_scan<128, true, false><<<(BATCH * 128) / 64, 64, 0, stream>>>(buf1, sp1, nullptr);

  // --- layer 2: BM=128, BN=64. ---
  gemm_deep2<4, 1, 32, false, true><<<dim3(1, M / 128), 256, 0, stream>>>(
      sp1, hi2, lo2, u2, c2, buf2, 64, 128);
  lif_scan<64, false, true><<<(BATCH * 64) / 64, 64, 0, stream>>>(buf2, nullptr, tsum);

  finalize<<<1, 64, 0, stream>>>(tsum, Wc, bc, out);
}